// Round 5
// baseline (310.145 us; speedup 1.0000x reference)
//
#include <hip/hip_runtime.h>

// HolographicConv: out = Re(ifft2(fft2(x) * W)), B == C_out == 16 -> pure
// elementwise complex multiply in frequency space per (b,c) image slice.
// 256 images of 256x256 complex64.
//
// Intermediate TRANSPOSED: wsT[v*256 + k_u].
//   K1: FFT over u.  K2: FFT over v + mul W + IFFT over v (in-place).
//   K3: IFFT over k_u, write Re/65536.
//
// FFT-256 = radix-4 Stockham, 4 stages, one wave per transform, pair of
// columns packed in float4 (A.re,A.im,B.re,B.im) -> every LDS access b128.
// This round (R4 was latency-bound: no pipe >40%, occupancy 36%):
//  - ILP-2: both pair-chains interleaved per stage (fft256_p2) -> two
//    independent LDS dependency chains per wave.
//  - XOR-swizzled [256][8] tile (no pad) -> 32.0 KiB LDS -> 5 blocks/CU.
//  - w1-only twiddle regs (w2=w1^2, w3=w1*w2 per stage) to fit VGPR<=102.

#define PI_F 3.14159265358979323846f

__device__ __forceinline__ float2 cmul2(float2 a, float2 b){
  return make_float2(a.x*b.x - a.y*b.y, a.x*b.y + a.y*b.x);
}
__device__ __forceinline__ float4 f4add(float4 a, float4 b){
  return make_float4(a.x+b.x, a.y+b.y, a.z+b.z, a.w+b.w);
}
__device__ __forceinline__ float4 f4sub(float4 a, float4 b){
  return make_float4(a.x-b.x, a.y-b.y, a.z-b.z, a.w-b.w);
}
__device__ __forceinline__ float4 mulI (float4 t){ return make_float4(-t.y, t.x, -t.w, t.z); }
__device__ __forceinline__ float4 mulmI(float4 t){ return make_float4( t.y,-t.x,  t.w,-t.z); }
__device__ __forceinline__ float4 cmul_pw(float4 a, float2 w){
  return make_float4(a.x*w.x - a.y*w.y, a.x*w.y + a.y*w.x,
                     a.z*w.x - a.w*w.y, a.z*w.y + a.w*w.x);
}
__device__ __forceinline__ float4 cmul_p4(float4 a, float4 w){
  return make_float4(a.x*w.x - a.y*w.y, a.x*w.y + a.y*w.x,
                     a.z*w.z - a.w*w.w, a.z*w.w + a.w*w.z);
}

// Stockham scratch swizzle (f4 cells).
__device__ __forceinline__ int SW(int e){ return e ^ (e >> 4); }
// Transpose-tile swizzle: cell (row u, pair c) -> conflict-free both ways.
__device__ __forceinline__ int TC(int u, int c){ return u*8 + (c ^ (u & 7)); }

template<int DIR>  // +1: forward e^{-i}, -1: inverse e^{+i} (unnormalized)
__device__ __forceinline__ void bfly4p(float4 v[4], float2 w1, float2 w2, float2 w3)
{
  float4 apc = f4add(v[0], v[2]), amc = f4sub(v[0], v[2]);
  float4 bpd = f4add(v[1], v[3]), bmd = f4sub(v[1], v[3]);
  float4 jb  = (DIR > 0) ? mulI(bmd) : mulmI(bmd);
  v[0] = f4add(apc, bpd);
  v[1] = cmul_pw(f4sub(amc, jb), w1);
  v[2] = cmul_pw(f4sub(apc, bpd), w2);
  v[3] = cmul_pw(f4add(amc, jb), w3);
}

// Two interleaved pair-FFT-256s (ILP-2). sa/sb = 256-f4 scratch regions.
template<int DIR>
__device__ __forceinline__ void fft256_p2(float4 va[4], float4 vb[4],
                                          float4* sa, float4* sb,
                                          const float2 (&tw1)[3], int lane)
{
  #pragma unroll
  for (int st = 0; st < 3; ++st) {               // s = 1, 4, 16
    const int s  = 1 << (2*st);
    const int ps = lane & ~(s-1);
    const int q  = lane &  (s-1);
    float2 w1 = tw1[st];
    if (DIR < 0) w1.y = -w1.y;
    const float2 w2 = cmul2(w1, w1);
    const float2 w3 = cmul2(w1, w2);
    bfly4p<DIR>(va, w1, w2, w3);
    bfly4p<DIR>(vb, w1, w2, w3);
    const int dbase = q + 4*ps;
    __builtin_amdgcn_wave_barrier();
    sa[SW(dbase + 0*s)] = va[0];  sb[SW(dbase + 0*s)] = vb[0];
    sa[SW(dbase + 1*s)] = va[1];  sb[SW(dbase + 1*s)] = vb[1];
    sa[SW(dbase + 2*s)] = va[2];  sb[SW(dbase + 2*s)] = vb[2];
    sa[SW(dbase + 3*s)] = va[3];  sb[SW(dbase + 3*s)] = vb[3];
    __builtin_amdgcn_wave_barrier();             // in-order LDS per wave
    va[0] = sa[SW(lane +   0)];   vb[0] = sb[SW(lane +   0)];
    va[1] = sa[SW(lane +  64)];   vb[1] = sb[SW(lane +  64)];
    va[2] = sa[SW(lane + 128)];   vb[2] = sb[SW(lane + 128)];
    va[3] = sa[SW(lane + 192)];   vb[3] = sb[SW(lane + 192)];
    __builtin_amdgcn_wave_barrier();
  }
  const float2 one = make_float2(1.f, 0.f);      // s=64 stage: unit twiddles
  bfly4p<DIR>(va, one, one, one);
  bfly4p<DIR>(vb, one, one, one);
}

// w1 per stage only: tw1[st] = exp(-2*pi*i*(lane&~(s-1))/256).
__device__ __forceinline__ void make_tw1(float2 (&tw1)[3], int lane)
{
  #pragma unroll
  for (int st = 0; st < 3; ++st) {
    const int s  = 1 << (2*st);
    const int ps = lane & ~(s-1);
    float sv, cv;
    sincosf(-2.0f * PI_F * (float)ps / 256.0f, &sv, &cv);
    tw1[st] = make_float2(cv, sv);
  }
}

// ---------------- K1: FFT over u, write wsT[v][k_u] ------------------------
__global__ __launch_bounds__(256, 5) void k_colfft(const float* __restrict__ xr,
                                                   const float* __restrict__ xi,
                                                   float2* __restrict__ wsT)
{
  __shared__ float4 pool[2048];        // tile [256][8] swz; scr aliases all
  const int tid  = threadIdx.x;
  const int imgl = blockIdx.x >> 4;
  const int v0   = (blockIdx.x & 15) * 16;
  const size_t ib = (size_t)imgl * 65536;
  const int q  = tid & 3;              // 4 threads per row
  const int h0 = tid >> 2;             // 0..63
  #pragma unroll
  for (int t = 0; t < 4; ++t) {
    const int u = h0 + 64*t;
    float4 r4 = *(const float4*)(xr + ib + (size_t)u*256 + v0 + 4*q);
    float4 i4 = *(const float4*)(xi + ib + (size_t)u*256 + v0 + 4*q);
    pool[TC(u, 2*q    )] = make_float4(r4.x, i4.x, r4.y, i4.y);
    pool[TC(u, 2*q + 1)] = make_float4(r4.z, i4.z, r4.w, i4.w);
  }
  const int wave = tid >> 6, lane = tid & 63;
  float2 tw1[3];
  make_tw1(tw1, lane);
  __syncthreads();
  const int cpa = wave*2, cpb = wave*2 + 1;
  float4 va[4], vb[4];
  #pragma unroll
  for (int r = 0; r < 4; ++r) { va[r] = pool[TC(lane + 64*r, cpa)];
                                vb[r] = pool[TC(lane + 64*r, cpb)]; }
  __syncthreads();                     // tile reads done before scr clobber
  float4* sa = pool + wave*512;
  float4* sb = sa + 256;
  fft256_p2<1>(va, vb, sa, sb, tw1, lane);
  {
    float2* oA = wsT + ib + (size_t)(v0 + 2*cpa)*256;
    float2* oB = oA + 256;
    #pragma unroll
    for (int r = 0; r < 4; ++r) {
      const int l = lane + 64*r;
      oA[l] = make_float2(va[r].x, va[r].y);
      oB[l] = make_float2(va[r].z, va[r].w);
    }
  }
  {
    float2* oA = wsT + ib + (size_t)(v0 + 2*cpb)*256;
    float2* oB = oA + 256;
    #pragma unroll
    for (int r = 0; r < 4; ++r) {
      const int l = lane + 64*r;
      oA[l] = make_float2(vb[r].x, vb[r].y);
      oB[l] = make_float2(vb[r].z, vb[r].w);
    }
  }
}

// ---------------- K2: FFT over v, * W, IFFT over v (in-place on wsT) -------
__global__ __launch_bounds__(256, 5) void k_rowpass(float2* __restrict__ wsT,
                                                    const float* __restrict__ wr,
                                                    const float* __restrict__ wi,
                                                    int img0)
{
  __shared__ float4 pool[2048];        // tile [256][8] swz; scr aliases all
  const int tid  = threadIdx.x;
  const int imgl = blockIdx.x >> 4;
  const int k0   = (blockIdx.x & 15) * 16;
  const size_t ib = (size_t)imgl * 65536;
  const size_t wb = (size_t)(img0 + imgl) * 65536;
  const int c8 = tid & 7;              // 8 threads per row
  const int h0 = tid >> 3;             // 0..31
  #pragma unroll
  for (int t = 0; t < 8; ++t) {
    const int v = h0 + 32*t;
    pool[TC(v, c8)] = *(const float4*)(wsT + ib + (size_t)v*256 + k0 + 2*c8);
  }
  const int wave = tid >> 6, lane = tid & 63;
  float2 tw1[3];
  make_tw1(tw1, lane);
  __syncthreads();
  const int cpa = wave*2, cpb = wave*2 + 1;
  float4 va[4], vb[4];
  #pragma unroll
  for (int r = 0; r < 4; ++r) { va[r] = pool[TC(lane + 64*r, cpa)];
                                vb[r] = pool[TC(lane + 64*r, cpb)]; }
  __syncthreads();                     // tile reads done before scr clobber
  // W loads AFTER the barrier (hipcc drains vmcnt at s_barrier): the ~900cy
  // HBM latency hides under the forward FFT below.
  const size_t ba = wb + (size_t)(k0 + 2*cpa)*256;
  const size_t bb = wb + (size_t)(k0 + 2*cpb)*256;
  float4 wva[4], wvb[4];
  #pragma unroll
  for (int r = 0; r < 4; ++r) {
    const int l = lane + 64*r;
    wva[r] = make_float4(wr[ba + l], wi[ba + l], wr[ba + 256 + l], wi[ba + 256 + l]);
    wvb[r] = make_float4(wr[bb + l], wi[bb + l], wr[bb + 256 + l], wi[bb + 256 + l]);
  }
  float4* sa = pool + wave*512;
  float4* sb = sa + 256;
  fft256_p2<1>(va, vb, sa, sb, tw1, lane);
  #pragma unroll
  for (int r = 0; r < 4; ++r) { va[r] = cmul_p4(va[r], wva[r]);
                                vb[r] = cmul_p4(vb[r], wvb[r]); }
  fft256_p2<-1>(va, vb, sa, sb, tw1, lane);
  __syncthreads();                     // all waves done with scr
  #pragma unroll
  for (int r = 0; r < 4; ++r) { pool[TC(lane + 64*r, cpa)] = va[r];
                                pool[TC(lane + 64*r, cpb)] = vb[r]; }
  __syncthreads();
  #pragma unroll
  for (int t = 0; t < 8; ++t) {
    const int v = h0 + 32*t;
    *(float4*)(wsT + ib + (size_t)v*256 + k0 + 2*c8) = pool[TC(v, c8)];
  }
}

// ---------------- K3: IFFT over k_u, write Re/65536 ------------------------
__global__ __launch_bounds__(256, 5) void k_rowifft(const float2* __restrict__ wsT,
                                                    float* __restrict__ out)
{
  __shared__ float4 pool[2048];        // scr 32KB; real out tile f2[256][8] aliases
  const int tid  = threadIdx.x;
  const int imgl = blockIdx.x >> 4;
  const int v0   = (blockIdx.x & 15) * 16;
  const size_t ib = (size_t)imgl * 65536;
  const int wave = tid >> 6, lane = tid & 63;
  float2 tw1[3];
  make_tw1(tw1, lane);
  const int cpa = wave*2, cpb = wave*2 + 1;
  float4 va[4], vb[4];
  {
    const float2* pA = wsT + ib + (size_t)(v0 + 2*cpa)*256;
    const float2* pB = pA + 256;
    const float2* pC = wsT + ib + (size_t)(v0 + 2*cpb)*256;
    const float2* pD = pC + 256;
    #pragma unroll
    for (int r = 0; r < 4; ++r) {
      const int l = lane + 64*r;
      float2 a = pA[l], b = pB[l], c = pC[l], d = pD[l];
      va[r] = make_float4(a.x, a.y, b.x, b.y);
      vb[r] = make_float4(c.x, c.y, d.x, d.y);
    }
  }
  float4* sa = pool + wave*512;
  float4* sb = sa + 256;
  fft256_p2<-1>(va, vb, sa, sb, tw1, lane);
  __syncthreads();                     // all waves done with scr
  float2* ot = (float2*)pool;          // [256][8] f2, XOR-swizzled
  const float sc = 1.0f / 65536.0f;
  #pragma unroll
  for (int r = 0; r < 4; ++r) {
    const int u = lane + 64*r;
    ot[TC(u, cpa)] = make_float2(va[r].x * sc, va[r].z * sc);
    ot[TC(u, cpb)] = make_float2(vb[r].x * sc, vb[r].z * sc);
  }
  __syncthreads();
  const int c4 = tid & 3, h0 = tid >> 2;
  #pragma unroll
  for (int t = 0; t < 4; ++t) {
    const int u = h0 + 64*t;
    float2 a = ot[TC(u, 2*c4)], b = ot[TC(u, 2*c4 + 1)];
    *(float4*)(out + ib + (size_t)u*256 + v0 + 4*c4) = make_float4(a.x, a.y, b.x, b.y);
  }
}

extern "C" void kernel_launch(void* const* d_in, const int* in_sizes, int n_in,
                              void* d_out, int out_size, void* d_ws, size_t ws_size,
                              hipStream_t stream)
{
  const float* xr = (const float*)d_in[0];
  const float* xi = (const float*)d_in[1];
  const float* wr = (const float*)d_in[2];
  const float* wi = (const float*)d_in[3];
  float* out = (float*)d_out;

  const int IMG = 256;                                    // B * C_IN
  const size_t per_img = (size_t)65536 * sizeof(float2);  // 512 KiB
  int ipc = (int)(ws_size / per_img);                     // images per chunk
  if (ipc < 1)   ipc = 1;
  if (ipc > IMG) ipc = IMG;
  float2* wsp = (float2*)d_ws;

  for (int img0 = 0; img0 < IMG; img0 += ipc) {
    const int n = (IMG - img0 < ipc) ? (IMG - img0) : ipc;
    k_colfft <<<dim3(n*16), dim3(256), 0, stream>>>(xr + (size_t)img0*65536,
                                                    xi + (size_t)img0*65536, wsp);
    k_rowpass<<<dim3(n*16), dim3(256), 0, stream>>>(wsp, wr, wi, img0);
    k_rowifft<<<dim3(n*16), dim3(256), 0, stream>>>(wsp, out + (size_t)img0*65536);
  }
}

// Round 6
// 197.729 us; speedup vs baseline: 1.5685x; 1.5685x over previous
//
#include <hip/hip_runtime.h>

// HolographicConv: out = Re(ifft2(fft2(x) * W)), B == C_out == 16 -> pure
// elementwise complex multiply in frequency space per (b,c) image slice.
// 256 images of 256x256 complex64.
//
// Intermediate TRANSPOSED: wsT[v*256 + k_u].
//   K1: FFT over u (tile transpose in).   K2: FFT over v + mul W + IFFT over v
//   (in-place, W coalesced to regs).      K3: IFFT over k_u (tile transpose out).
//
// FFT-256 = radix-4 Stockham, 4 stages (last LDS-free), one wave per
// transform, column pairs packed in float4 -> all LDS b128. ILP-2 chains.
// R6 changes vs R5 (R5 spilled: launch_bounds(,5) -> VGPR cap 96 -> VGPR=48
// + 250MB scratch traffic):
//  - __launch_bounds__(256, 4) everywhere (known-good codegen; 5 blocks/CU
//    still reachable because LDS = 32768 B exactly).
//  - one __sinf/__cosf + constant-select twiddle init (was 3 sincosf).
//  - per-image base POINTERS hoisted; all in-kernel offsets 32-bit ints.

#define PI_F 3.14159265358979323846f

__device__ __forceinline__ float2 cmul2(float2 a, float2 b){
  return make_float2(a.x*b.x - a.y*b.y, a.x*b.y + a.y*b.x);
}
__device__ __forceinline__ float4 f4add(float4 a, float4 b){
  return make_float4(a.x+b.x, a.y+b.y, a.z+b.z, a.w+b.w);
}
__device__ __forceinline__ float4 f4sub(float4 a, float4 b){
  return make_float4(a.x-b.x, a.y-b.y, a.z-b.z, a.w-b.w);
}
__device__ __forceinline__ float4 mulI (float4 t){ return make_float4(-t.y, t.x, -t.w, t.z); }
__device__ __forceinline__ float4 mulmI(float4 t){ return make_float4( t.y,-t.x,  t.w,-t.z); }
__device__ __forceinline__ float4 cmul_pw(float4 a, float2 w){
  return make_float4(a.x*w.x - a.y*w.y, a.x*w.y + a.y*w.x,
                     a.z*w.x - a.w*w.y, a.z*w.y + a.w*w.x);
}
__device__ __forceinline__ float4 cmul_p4(float4 a, float4 w){
  return make_float4(a.x*w.x - a.y*w.y, a.x*w.y + a.y*w.x,
                     a.z*w.z - a.w*w.w, a.z*w.w + a.w*w.z);
}

// Stockham scratch swizzle (f4 cells).
__device__ __forceinline__ int SW(int e){ return e ^ (e >> 4); }
// Transpose-tile swizzle: cell (row u, pair-col c), conflict-free both ways.
__device__ __forceinline__ int TC(int u, int c){ return u*8 + (c ^ (u & 7)); }

template<int DIR>  // +1: forward e^{-i}, -1: inverse e^{+i} (unnormalized)
__device__ __forceinline__ void bfly4p(float4 v[4], float2 w1, float2 w2, float2 w3)
{
  float4 apc = f4add(v[0], v[2]), amc = f4sub(v[0], v[2]);
  float4 bpd = f4add(v[1], v[3]), bmd = f4sub(v[1], v[3]);
  float4 jb  = (DIR > 0) ? mulI(bmd) : mulmI(bmd);
  v[0] = f4add(apc, bpd);
  v[1] = cmul_pw(f4sub(amc, jb), w1);
  v[2] = cmul_pw(f4sub(apc, bpd), w2);
  v[3] = cmul_pw(f4add(amc, jb), w3);
}

// Two interleaved pair-FFT-256s (ILP-2). sa/sb = 256-f4 scratch regions.
template<int DIR>
__device__ __forceinline__ void fft256_p2(float4 va[4], float4 vb[4],
                                          float4* sa, float4* sb,
                                          const float2 (&tw1)[3], int lane)
{
  #pragma unroll
  for (int st = 0; st < 3; ++st) {               // s = 1, 4, 16
    const int s  = 1 << (2*st);
    const int ps = lane & ~(s-1);
    const int q  = lane &  (s-1);
    float2 w1 = tw1[st];
    if (DIR < 0) w1.y = -w1.y;
    const float2 w2 = cmul2(w1, w1);
    const float2 w3 = cmul2(w1, w2);
    bfly4p<DIR>(va, w1, w2, w3);
    bfly4p<DIR>(vb, w1, w2, w3);
    const int dbase = q + 4*ps;
    __builtin_amdgcn_wave_barrier();
    sa[SW(dbase + 0*s)] = va[0];  sb[SW(dbase + 0*s)] = vb[0];
    sa[SW(dbase + 1*s)] = va[1];  sb[SW(dbase + 1*s)] = vb[1];
    sa[SW(dbase + 2*s)] = va[2];  sb[SW(dbase + 2*s)] = vb[2];
    sa[SW(dbase + 3*s)] = va[3];  sb[SW(dbase + 3*s)] = vb[3];
    __builtin_amdgcn_wave_barrier();             // in-order LDS per wave
    va[0] = sa[SW(lane +   0)];   vb[0] = sb[SW(lane +   0)];
    va[1] = sa[SW(lane +  64)];   vb[1] = sb[SW(lane +  64)];
    va[2] = sa[SW(lane + 128)];   vb[2] = sb[SW(lane + 128)];
    va[3] = sa[SW(lane + 192)];   vb[3] = sb[SW(lane + 192)];
    __builtin_amdgcn_wave_barrier();
  }
  const float2 one = make_float2(1.f, 0.f);      // s=64 stage: unit twiddles
  bfly4p<DIR>(va, one, one, one);
  bfly4p<DIR>(vb, one, one, one);
}

// tw1[st] = exp(-2*pi*i*(lane & ~(s-1))/256), s = 1,4,16.
// One sin/cos pair + constant-select corrections: w^(lane&~3) = w^lane *
// w^-(lane&3); w^(lane&~15) = w^(lane&~3) * w^-(lane&12). w^-k = (cos, +sin).
__device__ __forceinline__ void make_tw1(float2 (&tw1)[3], int lane)
{
  const float ang = -2.0f * PI_F * (float)lane / 256.0f;
  tw1[0] = make_float2(__cosf(ang), __sinf(ang));          // w^lane
  const int l3 = lane & 3, l12 = lane & 12;
  const float2 i3 = (l3 == 0) ? make_float2(1.0f, 0.0f)
                  : (l3 == 1) ? make_float2(0.9996988186962f, 0.0245412285229f)
                  : (l3 == 2) ? make_float2(0.9987954562052f, 0.0490676743274f)
                  :             make_float2(0.9972904566787f, 0.0735645635997f);
  const float2 i12 = (l12 == 0) ? make_float2(1.0f, 0.0f)
                   : (l12 == 4) ? make_float2(0.9951847266722f, 0.0980171403296f)
                   : (l12 == 8) ? make_float2(0.9807852804032f, 0.1950903220161f)
                   :              make_float2(0.9569403357322f, 0.2902846772545f);
  tw1[1] = cmul2(tw1[0], i3);                              // w^(lane&~3)
  tw1[2] = cmul2(tw1[1], i12);                             // w^(lane&~15)
}

// ---------------- K1: FFT over u, write wsT[v][k_u] ------------------------
__global__ __launch_bounds__(256, 4) void k_colfft(const float* __restrict__ xr,
                                                   const float* __restrict__ xi,
                                                   float2* __restrict__ wsT)
{
  __shared__ float4 pool[2048];        // tile [256][8] swz; scr aliases all
  const int tid  = threadIdx.x;
  const int imgl = blockIdx.x >> 4;
  const int v0   = (blockIdx.x & 15) * 16;
  const float*  xrb = xr  + (size_t)imgl * 65536 + v0;
  const float*  xib = xi  + (size_t)imgl * 65536 + v0;
  float2*       wsb = wsT + (size_t)imgl * 65536 + (size_t)v0 * 256;
  const int q  = tid & 3;              // 4 threads per row
  const int h0 = tid >> 2;             // 0..63
  #pragma unroll
  for (int t = 0; t < 4; ++t) {
    const int u = h0 + 64*t;
    float4 r4 = *(const float4*)(xrb + u*256 + 4*q);
    float4 i4 = *(const float4*)(xib + u*256 + 4*q);
    pool[TC(u, 2*q    )] = make_float4(r4.x, i4.x, r4.y, i4.y);
    pool[TC(u, 2*q + 1)] = make_float4(r4.z, i4.z, r4.w, i4.w);
  }
  const int wave = tid >> 6, lane = tid & 63;
  float2 tw1[3];
  make_tw1(tw1, lane);
  __syncthreads();
  const int cpa = wave*2, cpb = wave*2 + 1;
  float4 va[4], vb[4];
  #pragma unroll
  for (int r = 0; r < 4; ++r) { va[r] = pool[TC(lane + 64*r, cpa)];
                                vb[r] = pool[TC(lane + 64*r, cpb)]; }
  __syncthreads();                     // tile reads done before scr clobber
  float4* sa = pool + wave*512;
  float4* sb = sa + 256;
  fft256_p2<1>(va, vb, sa, sb, tw1, lane);
  {
    float2* oA = wsb + 2*cpa*256;
    #pragma unroll
    for (int r = 0; r < 4; ++r) {
      const int l = lane + 64*r;
      oA[l]       = make_float2(va[r].x, va[r].y);
      oA[256 + l] = make_float2(va[r].z, va[r].w);
    }
  }
  {
    float2* oA = wsb + 2*cpb*256;
    #pragma unroll
    for (int r = 0; r < 4; ++r) {
      const int l = lane + 64*r;
      oA[l]       = make_float2(vb[r].x, vb[r].y);
      oA[256 + l] = make_float2(vb[r].z, vb[r].w);
    }
  }
}

// ---------------- K2: FFT over v, * W, IFFT over v (in-place on wsT) -------
__global__ __launch_bounds__(256, 4) void k_rowpass(float2* __restrict__ wsT,
                                                    const float* __restrict__ wr,
                                                    const float* __restrict__ wi,
                                                    int img0)
{
  __shared__ float4 pool[2048];        // tile [256][8] swz; scr aliases all
  const int tid  = threadIdx.x;
  const int imgl = blockIdx.x >> 4;
  const int k0   = (blockIdx.x & 15) * 16;
  float2*      wsb = wsT + (size_t)imgl * 65536 + k0;
  const size_t wb  = (size_t)(img0 + imgl) * 65536 + (size_t)k0 * 256;
  const int c8 = tid & 7;              // 8 threads per row
  const int h0 = tid >> 3;             // 0..31
  #pragma unroll
  for (int t = 0; t < 8; ++t) {
    const int v = h0 + 32*t;
    pool[TC(v, c8)] = *(const float4*)(wsb + v*256 + 2*c8);
  }
  const int wave = tid >> 6, lane = tid & 63;
  float2 tw1[3];
  make_tw1(tw1, lane);
  __syncthreads();
  const int cpa = wave*2, cpb = wave*2 + 1;
  float4 va[4], vb[4];
  #pragma unroll
  for (int r = 0; r < 4; ++r) { va[r] = pool[TC(lane + 64*r, cpa)];
                                vb[r] = pool[TC(lane + 64*r, cpb)]; }
  __syncthreads();                     // tile reads done before scr clobber
  // W loads AFTER the barrier (hipcc drains vmcnt at s_barrier): ~900cy HBM
  // latency hides under the forward FFT below.
  const float* wra = wr + wb + 2*cpa*256;
  const float* wia = wi + wb + 2*cpa*256;
  const float* wrb_ = wr + wb + 2*cpb*256;
  const float* wib_ = wi + wb + 2*cpb*256;
  float4 wva[4], wvb[4];
  #pragma unroll
  for (int r = 0; r < 4; ++r) {
    const int l = lane + 64*r;
    wva[r] = make_float4(wra[l],  wia[l],  wra[256 + l],  wia[256 + l]);
    wvb[r] = make_float4(wrb_[l], wib_[l], wrb_[256 + l], wib_[256 + l]);
  }
  float4* sa = pool + wave*512;
  float4* sb = sa + 256;
  fft256_p2<1>(va, vb, sa, sb, tw1, lane);
  #pragma unroll
  for (int r = 0; r < 4; ++r) { va[r] = cmul_p4(va[r], wva[r]);
                                vb[r] = cmul_p4(vb[r], wvb[r]); }
  fft256_p2<-1>(va, vb, sa, sb, tw1, lane);
  __syncthreads();                     // all waves done with scr
  #pragma unroll
  for (int r = 0; r < 4; ++r) { pool[TC(lane + 64*r, cpa)] = va[r];
                                pool[TC(lane + 64*r, cpb)] = vb[r]; }
  __syncthreads();
  #pragma unroll
  for (int t = 0; t < 8; ++t) {
    const int v = h0 + 32*t;
    *(float4*)(wsb + v*256 + 2*c8) = pool[TC(v, c8)];
  }
}

// ---------------- K3: IFFT over k_u, write Re/65536 ------------------------
__global__ __launch_bounds__(256, 4) void k_rowifft(const float2* __restrict__ wsT,
                                                    float* __restrict__ out)
{
  __shared__ float4 pool[2048];        // scr 32KB; real out tile f2[2048] aliases
  const int tid  = threadIdx.x;
  const int imgl = blockIdx.x >> 4;
  const int v0   = (blockIdx.x & 15) * 16;
  const float2* wsb = wsT + (size_t)imgl * 65536 + (size_t)v0 * 256;
  float*        ob  = out + (size_t)imgl * 65536 + v0;
  const int wave = tid >> 6, lane = tid & 63;
  float2 tw1[3];
  make_tw1(tw1, lane);
  const int cpa = wave*2, cpb = wave*2 + 1;
  float4 va[4], vb[4];
  {
    const float2* pA = wsb + 2*cpa*256;
    const float2* pC = wsb + 2*cpb*256;
    #pragma unroll
    for (int r = 0; r < 4; ++r) {
      const int l = lane + 64*r;
      float2 a = pA[l], b = pA[256 + l], c = pC[l], d = pC[256 + l];
      va[r] = make_float4(a.x, a.y, b.x, b.y);
      vb[r] = make_float4(c.x, c.y, d.x, d.y);
    }
  }
  float4* sa = pool + wave*512;
  float4* sb = sa + 256;
  fft256_p2<-1>(va, vb, sa, sb, tw1, lane);
  __syncthreads();                     // all waves done with scr
  float2* ot = (float2*)pool;          // [256][8] f2, XOR-swizzled
  const float sc = 1.0f / 65536.0f;
  #pragma unroll
  for (int r = 0; r < 4; ++r) {
    const int u = lane + 64*r;
    ot[TC(u, cpa)] = make_float2(va[r].x * sc, va[r].z * sc);
    ot[TC(u, cpb)] = make_float2(vb[r].x * sc, vb[r].z * sc);
  }
  __syncthreads();
  const int c4 = tid & 3, h0 = tid >> 2;
  #pragma unroll
  for (int t = 0; t < 4; ++t) {
    const int u = h0 + 64*t;
    float2 a = ot[TC(u, 2*c4)], b = ot[TC(u, 2*c4 + 1)];
    *(float4*)(ob + u*256 + 4*c4) = make_float4(a.x, a.y, b.x, b.y);
  }
}

extern "C" void kernel_launch(void* const* d_in, const int* in_sizes, int n_in,
                              void* d_out, int out_size, void* d_ws, size_t ws_size,
                              hipStream_t stream)
{
  const float* xr = (const float*)d_in[0];
  const float* xi = (const float*)d_in[1];
  const float* wr = (const float*)d_in[2];
  const float* wi = (const float*)d_in[3];
  float* out = (float*)d_out;

  const int IMG = 256;                                    // B * C_IN
  const size_t per_img = (size_t)65536 * sizeof(float2);  // 512 KiB
  int ipc = (int)(ws_size / per_img);                     // images per chunk
  if (ipc < 1)   ipc = 1;
  if (ipc > IMG) ipc = IMG;
  float2* wsp = (float2*)d_ws;

  for (int img0 = 0; img0 < IMG; img0 += ipc) {
    const int n = (IMG - img0 < ipc) ? (IMG - img0) : ipc;
    k_colfft <<<dim3(n*16), dim3(256), 0, stream>>>(xr + (size_t)img0*65536,
                                                    xi + (size_t)img0*65536, wsp);
    k_rowpass<<<dim3(n*16), dim3(256), 0, stream>>>(wsp, wr, wi, img0);
    k_rowifft<<<dim3(n*16), dim3(256), 0, stream>>>(wsp, out + (size_t)img0*65536);
  }
}

// Round 7
// 189.983 us; speedup vs baseline: 1.6325x; 1.0408x over previous
//
#include <hip/hip_runtime.h>

// HolographicConv: out = Re(ifft2(fft2(x) * W)), B == C_out == 16 -> pure
// elementwise complex multiply in frequency space per (b,c) image slice.
// 256 images of 256x256 complex64.  Intermediate TRANSPOSED: wsT[v*256 + k].
//
// R7: 16x16 four-step FFT-256. Lane m of a 16-lane group holds 16 elements
// of one column in registers; FFT-256 = in-reg FFT-16 (compile-time
// twiddles) -> per-lane twiddle chain -> ONE 16x16 LDS transpose -> in-reg
// FFT-16.  LDS round-trips per kernel drop ~2x vs the Stockham version
// (K2: 8 -> 4), all LDS access patterns at minimum bank touches, and all
// register arrays are single-chain constant-indexed (R5/R6 spilled on the
// interleaved-ILP structure; this removes it).
//
// Layouts (derived):
//   fwd:  in lane=n1,reg=n2 -> F16(reg) -> tw w256^(m*r) -> T -> F16 ->
//         out lane=k_lo, reg=k_hi   (element k = m + 16r)
//   inv:  in lane=l_lo,reg=l_hi -> F16 -> T -> tw w256^(+m*r) -> F16 ->
//         out lane=n_lo, reg=n_hi  (element n = m + 16r)
//   K2: fwd output layout == inverse input layout == W-coalesced. 2 T total.

#define PI_F 3.14159265358979323846f

__device__ __forceinline__ float2 cadd(float2 a, float2 b){ return make_float2(a.x+b.x, a.y+b.y); }
__device__ __forceinline__ float2 csub(float2 a, float2 b){ return make_float2(a.x-b.x, a.y-b.y); }
__device__ __forceinline__ float2 cmul2(float2 a, float2 b){
  return make_float2(a.x*b.x - a.y*b.y, a.x*b.y + a.y*b.x);
}

template<int DIR>
__device__ __forceinline__ float2 tw16c(float cx, float cy){   // conj for DIR<0
  return make_float2(cx, (DIR > 0) ? cy : -cy);
}

template<int DIR>   // +1: e^{-i} forward, -1: e^{+i} inverse (unnormalized)
__device__ __forceinline__ void bfly1(float2& a, float2& b, float2& c, float2& d)
{
  float2 apc = cadd(a,c), amc = csub(a,c);
  float2 bpd = cadd(b,d), bmd = csub(b,d);
  float2 jb = (DIR > 0) ? make_float2(-bmd.y, bmd.x)    //  i*(b-d)
                        : make_float2( bmd.y,-bmd.x);   // -i*(b-d)
  a = cadd(apc, bpd);
  b = csub(amc, jb);
  c = csub(apc, bpd);
  d = cadd(amc, jb);
}

template<int DIR>
__device__ __forceinline__ void bfly1t(float2& a, float2& b, float2& c, float2& d,
                                       float2 w1, float2 w2, float2 w3)
{
  bfly1<DIR>(a, b, c, d);
  b = cmul2(b, w1); c = cmul2(c, w2); d = cmul2(d, w3);
}

// In-register FFT-16 over the array index (natural order in and out).
// n = c + 4d; stage A: DFT4 over d (z[c][p] stored at x[c+4p], post-tw
// w16^(pc)); stage C: DFT4 over c at fixed p -> X[p+4q].
template<int DIR>
__device__ __forceinline__ void fft16(float2 (&x)[16])
{
  const float C1 = 0.92387953251128675613f, S1 = 0.38268343236508977173f;
  const float C2 = 0.70710678118654752440f;
  const float2 W1 = tw16c<DIR>( C1, -S1), W2 = tw16c<DIR>( C2, -C2);
  const float2 W3 = tw16c<DIR>( S1, -C1), W4 = tw16c<DIR>(0.f, -1.f);
  const float2 W6 = tw16c<DIR>(-C2, -C2), W9 = tw16c<DIR>(-C1,  S1);
  bfly1 <DIR>(x[0], x[4], x[8],  x[12]);
  bfly1t<DIR>(x[1], x[5], x[9],  x[13], W1, W2, W3);
  bfly1t<DIR>(x[2], x[6], x[10], x[14], W2, W4, W6);
  bfly1t<DIR>(x[3], x[7], x[11], x[15], W3, W6, W9);
  float2 y[16];
  #pragma unroll
  for (int p = 0; p < 4; ++p) {
    float2 a = x[4*p+0], b = x[4*p+1], c = x[4*p+2], d = x[4*p+3];
    bfly1<DIR>(a, b, c, d);
    y[p+0] = a; y[p+4] = b; y[p+8] = c; y[p+12] = d;
  }
  #pragma unroll
  for (int i = 0; i < 16; ++i) x[i] = y[i];
}

// x[r] *= w256^(DIR_sign * m * r): one fast sincos + iterative power chain.
template<int DIR>
__device__ __forceinline__ void twiddle256(float2 (&x)[16], int m)
{
  float sv, cv;
  __sincosf(((DIR > 0) ? -2.0f : 2.0f) * PI_F * (float)m * (1.0f/256.0f), &sv, &cv);
  const float2 w = make_float2(cv, sv);
  float2 p = w;
  x[1] = cmul2(x[1], p);
  #pragma unroll
  for (int r = 2; r < 16; ++r) { p = cmul2(p, w); x[r] = cmul2(x[r], p); }
}

// 16x16 transpose within a 16-lane group. M = this column's matrix
// (16 rows x pad 19 f2). Write M[reg][lane], read M[lane][reg].
// Banks: write 2m+const (4 touches/bank = b64 min); read 6m+2r (min too).
__device__ __forceinline__ void transpose16(float2 (&x)[16], float2* M, int m)
{
  __builtin_amdgcn_wave_barrier();
  #pragma unroll
  for (int r = 0; r < 16; ++r) M[r*19 + m] = x[r];
  __builtin_amdgcn_wave_barrier();               // in-order LDS per wave
  #pragma unroll
  for (int r = 0; r < 16; ++r) x[r] = M[m*19 + r];
  __builtin_amdgcn_wave_barrier();
}

// ---------------- K1: FFT over u, write wsT[v][k] --------------------------
__global__ __launch_bounds__(256, 4) void k_colfft(const float* __restrict__ xr,
                                                   const float* __restrict__ xi,
                                                   float2* __restrict__ wsT)
{
  __shared__ float2 pool[4864];   // tile f2[256][18] (4608) | mats 16x304, aliased
  const int tid  = threadIdx.x;
  const int imgl = blockIdx.x >> 4;
  const int v0   = (blockIdx.x & 15) * 16;
  const float* xrb = xr + (size_t)imgl * 65536 + v0;
  const float* xib = xi + (size_t)imgl * 65536 + v0;
  float2*      wsb = wsT + (size_t)imgl * 65536;
  const int q = tid & 3, h0 = tid >> 2;
  #pragma unroll
  for (int t = 0; t < 4; ++t) {
    const int u = h0 + 64*t;
    float4 r4 = *(const float4*)(xrb + u*256 + 4*q);
    float4 i4 = *(const float4*)(xib + u*256 + 4*q);
    float4* row = (float4*)(pool + u*18);        // 144B rows: 16B-aligned
    row[2*q]   = make_float4(r4.x, i4.x, r4.y, i4.y);
    row[2*q+1] = make_float4(r4.z, i4.z, r4.w, i4.w);
  }
  __syncthreads();
  const int lane = tid & 63, m = lane & 15;
  const int col  = (tid >> 6)*4 + (lane >> 4);   // column this lane serves
  float2 x[16];
  #pragma unroll
  for (int j = 0; j < 16; ++j) x[j] = pool[(m + 16*j)*18 + col];
  __syncthreads();                               // tile dead; mats overwrite
  float2* M = pool + col*304;
  fft16<1>(x);
  twiddle256<1>(x, m);
  transpose16(x, M, m);
  fft16<1>(x);
  float2* o = wsb + (size_t)(v0 + col) * 256;    // row v contiguous over k
  #pragma unroll
  for (int r = 0; r < 16; ++r) o[m + 16*r] = x[r];
}

// ---------------- K2: FFT over v, * W, IFFT over v (in-place on wsT) -------
__global__ __launch_bounds__(256, 4) void k_rowpass(float2* __restrict__ wsT,
                                                    const float* __restrict__ wr,
                                                    const float* __restrict__ wi,
                                                    int img0)
{
  __shared__ float2 pool[4864];   // tile f2[256][18] | mats 16x304, aliased
  const int tid  = threadIdx.x;
  const int imgl = blockIdx.x >> 4;
  const int k0   = (blockIdx.x & 15) * 16;
  float2* wsb = wsT + (size_t)imgl * 65536 + k0;
  const int c8 = tid & 7, h0 = tid >> 3;
  #pragma unroll
  for (int t = 0; t < 8; ++t) {
    const int v = h0 + 32*t;
    ((float4*)(pool + v*18))[c8] = *(const float4*)(wsb + v*256 + 2*c8);
  }
  __syncthreads();
  const int lane = tid & 63, m = lane & 15;
  const int col  = (tid >> 6)*4 + (lane >> 4);
  float2 x[16];
  #pragma unroll
  for (int j = 0; j < 16; ++j) x[j] = pool[(m + 16*j)*18 + col];
  __syncthreads();                               // tile dead; mats overwrite
  // W for this column, layout-matched to fwd output (l = m + 16r):
  // contiguous per group -> coalesced. Issued early; hides under fwd FFT.
  const size_t wcb = (size_t)(img0 + imgl) * 65536 + (size_t)(k0 + col) * 256 + m;
  const float* wrc = wr + wcb;
  const float* wic = wi + wcb;
  float2 wv[16];
  #pragma unroll
  for (int r = 0; r < 16; ++r) wv[r] = make_float2(wrc[16*r], wic[16*r]);
  float2* M = pool + col*304;
  fft16<1>(x);
  twiddle256<1>(x, m);
  transpose16(x, M, m);
  fft16<1>(x);                                   // lane=k_lo, reg=k_hi
  #pragma unroll
  for (int r = 0; r < 16; ++r) x[r] = cmul2(x[r], wv[r]);
  fft16<-1>(x);                                  // inverse: same layout in
  transpose16(x, M, m);
  twiddle256<-1>(x, m);
  fft16<-1>(x);                                  // lane=n_lo, reg=n_hi
  __syncthreads();                               // mats dead; tile writeback
  #pragma unroll
  for (int r = 0; r < 16; ++r) pool[(m + 16*r)*18 + col] = x[r];
  __syncthreads();
  #pragma unroll
  for (int t = 0; t < 8; ++t) {
    const int v = h0 + 32*t;
    *(float4*)(wsb + v*256 + 2*c8) = ((float4*)(pool + v*18))[c8];
  }
}

// ---------------- K3: IFFT over k, write Re/65536 --------------------------
__global__ __launch_bounds__(256, 4) void k_rowifft(const float2* __restrict__ wsT,
                                                    float* __restrict__ out)
{
  __shared__ float2 pool[4864];   // mats 16x304 | out-tile f32[256][20], aliased
  const int tid  = threadIdx.x;
  const int imgl = blockIdx.x >> 4;
  const int v0   = (blockIdx.x & 15) * 16;
  const float2* wsb = wsT + (size_t)imgl * 65536;
  float*        ob  = out + (size_t)imgl * 65536 + v0;
  const int lane = tid & 63, m = lane & 15;
  const int col  = (tid >> 6)*4 + (lane >> 4);
  const float2* src = wsb + (size_t)(v0 + col) * 256;  // row v: contiguous k
  float2 x[16];
  #pragma unroll
  for (int r = 0; r < 16; ++r) x[r] = src[m + 16*r];   // coalesced direct
  float2* M = pool + col*304;
  fft16<-1>(x);
  transpose16(x, M, m);
  twiddle256<-1>(x, m);
  fft16<-1>(x);                                  // lane=n_lo(u), reg=n_hi
  __syncthreads();                               // mats dead; out-tile
  float* ot = (float*)pool;                      // [256][20] f32
  const float sc = 1.0f / 65536.0f;
  #pragma unroll
  for (int r = 0; r < 16; ++r) ot[(m + 16*r)*20 + col] = x[r].x * sc;
  __syncthreads();
  const int q = tid & 3, h0 = tid >> 2;
  #pragma unroll
  for (int t = 0; t < 4; ++t) {
    const int u = h0 + 64*t;
    *(float4*)(ob + u*256 + 4*q) = *(const float4*)(ot + u*20 + 4*q);
  }
}

extern "C" void kernel_launch(void* const* d_in, const int* in_sizes, int n_in,
                              void* d_out, int out_size, void* d_ws, size_t ws_size,
                              hipStream_t stream)
{
  const float* xr = (const float*)d_in[0];
  const float* xi = (const float*)d_in[1];
  const float* wr = (const float*)d_in[2];
  const float* wi = (const float*)d_in[3];
  float* out = (float*)d_out;

  const int IMG = 256;                                    // B * C_IN
  const size_t per_img = (size_t)65536 * sizeof(float2);  // 512 KiB
  int ipc = (int)(ws_size / per_img);                     // images per chunk
  if (ipc < 1)   ipc = 1;
  if (ipc > IMG) ipc = IMG;
  float2* wsp = (float2*)d_ws;

  for (int img0 = 0; img0 < IMG; img0 += ipc) {
    const int n = (IMG - img0 < ipc) ? (IMG - img0) : ipc;
    k_colfft <<<dim3(n*16), dim3(256), 0, stream>>>(xr + (size_t)img0*65536,
                                                    xi + (size_t)img0*65536, wsp);
    k_rowpass<<<dim3(n*16), dim3(256), 0, stream>>>(wsp, wr, wi, img0);
    k_rowifft<<<dim3(n*16), dim3(256), 0, stream>>>(wsp, out + (size_t)img0*65536);
  }
}